// Round 2
// baseline (284.242 us; speedup 1.0000x reference)
//
#include <hip/hip_runtime.h>

#define BB 16
#define NN 2000
#define HH 720
#define WW 1280
#define NPT (BB*NN)           // 32000 keypoints
#define PT_BLOCKS (NPT/32)    // 1000 blocks, 4 waves x 8 points each
#define CHUNK (NN/8)          // 250 candidates per chunk-lane
#define KNN_BX ((NN+31)/32)   // 63 blocks per batch

static __device__ __forceinline__ unsigned u_min(unsigned a, unsigned b){ return a < b ? a : b; }
static __device__ __forceinline__ unsigned u_max(unsigned a, unsigned b){ return a > b ? a : b; }

// ---------------- bilinear sample, exact reference semantics (fallback) -----
__device__ __forceinline__ float bilin(const float* __restrict__ im, float px, float py) {
    px = fminf(fmaxf(px, 0.f), (float)(WW - 1));
    py = fminf(fmaxf(py, 0.f), (float)(HH - 1));
    float x0f = floorf(px), y0f = floorf(py);
    float fx = px - x0f, fy = py - y0f;
    int x0 = min(max((int)x0f, 0), WW - 1);
    int x1 = min(x0 + 1, WW - 1);
    int y0 = min(max((int)y0f, 0), HH - 1);
    int y1 = min(y0 + 1, HH - 1);
    const float* r0 = im + (size_t)y0 * WW;
    const float* r1 = im + (size_t)y1 * WW;
    float v00 = r0[x0], v01 = r0[x1], v10 = r1[x0], v11 = r1[x1];
    return (v00 * (1.f - fx) + v01 * fx) * (1.f - fy)
         + (v10 * (1.f - fx) + v11 * fx) * fy;
}

// ---------------- Kernel A: patch loss + projection -------------------------
// 4 waves/block, each wave processes 8 points sequentially.
// Interior fast path: one 8x8 region pixel per lane + shuffles (uniform fx,fy).
__global__ __launch_bounds__(256) void point_kernel(
    const float* __restrict__ lg, const float* __restrict__ rg,
    const float* __restrict__ kpl, const float* __restrict__ kpr,
    const float* __restrict__ scores, const float* __restrict__ Q,
    float4* __restrict__ pts, float* __restrict__ partials,
    float* __restrict__ batch_acc)
{
    if (blockIdx.x == 0 && threadIdx.x < BB * 4) batch_acc[threadIdx.x] = 0.f;

    int wave = threadIdx.x >> 6, lane = threadIdx.x & 63;
    int rr = lane / 7, ci = lane - rr * 7;      // sample (row,col) for lane<49
    int s00 = lane + rr;                        // = rr*8+ci in 8x8 region
    if (s00 > 54) s00 = 54;                     // keep shfl idx valid for lanes>=49
    int reg_r = lane >> 3, reg_c = lane & 7;    // region-load position

    float a0=0.f,a1=0.f,a2=0.f,a3=0.f,a4=0.f,a5=0.f,a6=0.f;

    for (int it = 0; it < 8; ++it) {
        int pt = blockIdx.x * 32 + wave * 8 + it;
        int b = pt / NN;
        const float* iml = lg + (size_t)b * (HH * WW);
        const float* imr = rg + (size_t)b * (HH * WW);
        float kxl = kpl[2*pt], kyl = kpl[2*pt+1];
        float kxr = kpr[2*pt], kyr = kpr[2*pt+1];
        float sc  = scores[pt];

        // ---- left patch ----
        float flx = floorf(kxl), fly = floorf(kyl);
        int xbl = (int)flx - 3, ybl = (int)fly - 3;
        float fxl = kxl - flx, fyl = kyl - fly;
        float vl = 0.f;
        if (xbl >= 0 && xbl <= WW-8 && ybl >= 0 && ybl <= HH-8) {  // wave-uniform
            float reg = iml[(size_t)(ybl + reg_r) * WW + xbl + reg_c];
            float v00 = __shfl(reg, s00,     64);
            float v01 = __shfl(reg, s00 + 1, 64);
            float v10 = __shfl(reg, s00 + 8, 64);
            float v11 = __shfl(reg, s00 + 9, 64);
            vl = (v00*(1.f-fxl) + v01*fxl)*(1.f-fyl) + (v10*(1.f-fxl) + v11*fxl)*fyl;
        } else if (lane < 49) {
            vl = bilin(iml, kxl + (float)(ci-3), kyl + (float)(rr-3));
        }
        // ---- right patch ----
        float frx = floorf(kxr), fry = floorf(kyr);
        int xbr = (int)frx - 3, ybr = (int)fry - 3;
        float fxr = kxr - frx, fyr = kyr - fry;
        float vr = 0.f;
        if (xbr >= 0 && xbr <= WW-8 && ybr >= 0 && ybr <= HH-8) {  // wave-uniform
            float reg = imr[(size_t)(ybr + reg_r) * WW + xbr + reg_c];
            float v00 = __shfl(reg, s00,     64);
            float v01 = __shfl(reg, s00 + 1, 64);
            float v10 = __shfl(reg, s00 + 8, 64);
            float v11 = __shfl(reg, s00 + 9, 64);
            vr = (v00*(1.f-fxr) + v01*fxr)*(1.f-fyr) + (v10*(1.f-fxr) + v11*fxr)*fyr;
        } else if (lane < 49) {
            vr = bilin(imr, kxr + (float)(ci-3), kyr + (float)(rr-3));
        }

        float adiff = (lane < 49) ? fabsf(vl - vr) : 0.f;
        float cl = __shfl(vl, 24, 64);   // center sample (3,3)
        float cr = __shfl(vr, 24, 64);
        #pragma unroll
        for (int off = 32; off > 0; off >>= 1) adiff += __shfl_down(adiff, off, 64);

        if (lane == 0) {
            float diff = adiff / 49.f;
            float isb  = (cl > 0.02f) ? 1.f : 0.f;   // BRIGHT
            float w    = sc * isb;
            float ydiff = fabsf(kyl - kyr);
            float dc = fabsf(cl - cr);
            float sl1 = (dc < 1.f) ? 0.5f * dc * dc : dc - 0.5f;

            const float* q = Q + b * 16;
            float dsp = kxl - kxr;
            float p0 = q[0]*kxl + q[1]*kyl + q[2]*dsp  + q[3];
            float p1 = q[4]*kxl + q[5]*kyl + q[6]*dsp  + q[7];
            float p2 = q[8]*kxl + q[9]*kyl + q[10]*dsp + q[11];
            float p3 = q[12]*kxl + q[13]*kyl + q[14]*dsp + q[15];
            float Wc = fmaxf(p3, 1e-6f);
            float X = p0 / Wc, Y = p1 / Wc, Z = p2 / Wc;
            bool valid = (Z > 100.f) && (Z < 30000.f) && (sc > 0.1f);
            float x  = X / 1000.f;
            float hh = Y / 1000.f;
            float y  = Z / 1000.f;
            float sq = x * x + y * y;
            if (!valid) { x = 0.f; y = 0.f; sq = 1e18f; }   // sentinel
            pts[pt] = make_float4(x, y, sq, hh);

            a0 += sc;  a1 += ydiff * sc;  a2 += ydiff;
            a3 += w;   a4 += diff * w;    a5 += sl1 * w;
            a6 += (sc > 0.1f) ? 1.f : 0.f;
        }
    }

    __shared__ float red[4][7];
    if (lane == 0) {
        red[wave][0]=a0; red[wave][1]=a1; red[wave][2]=a2; red[wave][3]=a3;
        red[wave][4]=a4; red[wave][5]=a5; red[wave][6]=a6;
    }
    __syncthreads();
    if (threadIdx.x < 8) {
        int k = threadIdx.x;
        float v = 0.f;
        if (k < 7) v = red[0][k] + red[1][k] + red[2][k] + red[3][k];
        partials[blockIdx.x * 8 + k] = v;
    }
}

// ---------------- Kernel B: KNN via packed-key min/max network --------------
// wave = 8 points x 8 chunks; key = (d2_bits & ~0x7FF) | m  (uint order == d2 order)
__global__ __launch_bounds__(256) void knn_kernel(
    const float4* __restrict__ pts, float* __restrict__ batch_acc)
{
    __shared__ float4 tile[NN];   // 32 KB
    int b = blockIdx.y;
    for (int i = threadIdx.x; i < NN; i += 256) tile[i] = pts[b * NN + i];
    __syncthreads();

    int lane = threadIdx.x & 63, wave = threadIdx.x >> 6;
    int p = lane >> 3, c = lane & 7;
    int n = blockIdx.x * 32 + wave * 8 + p;

    unsigned K0=0xFFFFFFFFu,K1=0xFFFFFFFFu,K2=0xFFFFFFFFu,K3=0xFFFFFFFFu,K4=0xFFFFFFFFu;
    bool act = false;
    float sqn = 0.f, nx2 = 0.f, ny2 = 0.f, xn = 0.f, yn = 0.f, hn = 0.f;
    if (n < NN) {
        float4 me = tile[n];
        act = (me.z < 1e17f);
        xn = me.x; yn = me.y; sqn = me.z; hn = me.w;
        nx2 = -2.f * me.x; ny2 = -2.f * me.y;
    }

#define INSERT(u) do { unsigned _u = (u); \
        K4 = u_min(K4, u_max(K3, _u)); \
        K3 = u_min(K3, u_max(K2, _u)); \
        K2 = u_min(K2, u_max(K1, _u)); \
        K1 = u_min(K1, u_max(K0, _u)); \
        K0 = u_min(K0, _u); } while (0)

    if (act) {
        int m0 = c * CHUNK;
        #pragma unroll 5
        for (int mm = 0; mm < CHUNK; ++mm) {
            int m = m0 + mm;
            float4 o = tile[m];
            float t = fmaf(ny2, o.y, o.z);
            t = fmaf(nx2, o.x, t);
            float d2 = fmaxf(t + sqn, 1e-12f);
            unsigned u = (__float_as_uint(d2) & 0xFFFFF800u) | (unsigned)m;
            INSERT(u);
        }
        // remove self (index match) — cascade shift
        unsigned nn = (unsigned)n;
        bool b0 =      (K0 & 2047u) == nn;
        bool b1 = b0 | ((K1 & 2047u) == nn);
        bool b2 = b1 | ((K2 & 2047u) == nn);
        bool b3 = b2 | ((K3 & 2047u) == nn);
        bool b4 = b3 | ((K4 & 2047u) == nn);
        K0 = b0 ? K1 : K0;
        K1 = b1 ? K2 : K1;
        K2 = b2 ? K3 : K2;
        K3 = b3 ? K4 : K3;
        K4 = b4 ? 0xFFFFFFFFu : K4;
    }

    // tree-merge the 8 chunk lists of each point (all lanes participate)
    #pragma unroll
    for (int off = 1; off < 8; off <<= 1) {
        unsigned B0 = (unsigned)__shfl_xor((int)K0, off, 64);
        unsigned B1 = (unsigned)__shfl_xor((int)K1, off, 64);
        unsigned B2 = (unsigned)__shfl_xor((int)K2, off, 64);
        unsigned B3 = (unsigned)__shfl_xor((int)K3, off, 64);
        unsigned B4 = (unsigned)__shfl_xor((int)K4, off, 64);
        INSERT(B0); INSERT(B1); INSERT(B2); INSERT(B3); INSERT(B4);
    }
#undef INSERT

    float ls = 0.f, pen = 0.f, hacc = 0.f, cnt = 0.f;
    if (act && c == 0) {
        float hsum = 0.f;
        unsigned Ks0=K0, Ks1=K1, Ks2=K2, Ks3=K3, Ks4=K4;
        unsigned idx[5] = {Ks0 & 2047u, Ks1 & 2047u, Ks2 & 2047u, Ks3 & 2047u, Ks4 & 2047u};
        #pragma unroll
        for (int j = 0; j < 5; ++j) {
            float4 o = tile[idx[j]];
            float dot = xn * o.x + yn * o.y;
            float d2 = (sqn + o.z) - 2.f * dot;        // exact recompute
            float nd = fmaxf(sqrtf(fmaxf(d2, 1e-12f)), 0.001f);
            hsum += o.w;
            pen  += fmaxf(fabsf(o.w - hn) / nd - 0.4f, 0.f);
        }
        float lm = hsum / 5.f;
        float dd = fabsf(hn - lm);
        ls = (dd < 0.01f) ? 0.5f * dd * dd / 0.01f : dd - 0.005f;  // smooth_l1 beta=0.01
        hacc = hn;
        cnt  = 1.f;
    }
    // reduce lanes {0,8,...,56} -> lane 0
    #pragma unroll
    for (int off = 32; off >= 8; off >>= 1) {
        ls   += __shfl_down(ls,   off, 64);
        pen  += __shfl_down(pen,  off, 64);
        hacc += __shfl_down(hacc, off, 64);
        cnt  += __shfl_down(cnt,  off, 64);
    }
    if (lane == 0) {
        atomicAdd(&batch_acc[b * 4 + 0], cnt);
        atomicAdd(&batch_acc[b * 4 + 1], ls);
        atomicAdd(&batch_acc[b * 4 + 2], pen);
        atomicAdd(&batch_acc[b * 4 + 3], hacc);
    }
}

// ---------------- Kernel C: final scalar epilogue ---------------------------
__global__ __launch_bounds__(256) void final_kernel(
    const float* __restrict__ partials, const float* __restrict__ batch_acc,
    float* __restrict__ out)
{
    float s[8] = {0,0,0,0,0,0,0,0};
    for (int r = threadIdx.x; r < PT_BLOCKS; r += 256) {
        #pragma unroll
        for (int k = 0; k < 8; ++k) s[k] += partials[r * 8 + k];
    }
    #pragma unroll
    for (int off = 32; off > 0; off >>= 1) {
        #pragma unroll
        for (int k = 0; k < 8; ++k) s[k] += __shfl_down(s[k], off, 64);
    }
    __shared__ float wsum_s[4][8];
    int wv = threadIdx.x >> 6, lane = threadIdx.x & 63;
    if (lane == 0) {
        #pragma unroll
        for (int k = 0; k < 8; ++k) wsum_s[wv][k] = s[k];
    }
    __syncthreads();
    if (threadIdx.x == 0) {
        float t[8];
        #pragma unroll
        for (int k = 0; k < 8; ++k)
            t[k] = wsum_s[0][k] + wsum_s[1][k] + wsum_s[2][k] + wsum_s[3][k];
        float ssc = t[0], yds = t[1], yd = t[2], wsum = t[3], dw = t[4], iw = t[5], cnts = t[6];

        float l_epi = (ssc > 1e-4f) ? yds / fmaxf(ssc, 1e-12f) : yd / (float)NPT;
        float safe = fmaxf(wsum, 1e-12f);
        float l_photo = (wsum > 1e-4f) ? (dw / safe + iw / safe) : 0.f;

        float als = 0.f, alsl = 0.f, alz = 0.f, okc = 0.f;
        for (int b = 0; b < BB; ++b) {
            float nvf  = batch_acc[b * 4 + 0];
            float lsb  = batch_acc[b * 4 + 1];
            float penb = batch_acc[b * 4 + 2];
            float hb   = batch_acc[b * 4 + 3];
            float nv = fmaxf(nvf, 1.f);
            float ok = (nvf >= 10.f) ? 1.f : 0.f;
            als  += ok * (lsb / nv);
            alsl += ok * (penb / (nv * 5.f));   // K = 5
            alz  += ok * fabsf(hb / nv);
            okc  += ok;
        }
        float nb = fmaxf(okc, 1.f);
        bool gate = (cnts >= 10.f) && (okc > 0.f);
        out[0] = l_photo;
        out[1] = l_epi;
        out[2] = gate ? als / nb : 0.f;
        out[3] = gate ? alsl / nb : 0.f;
        out[4] = gate ? alz / nb : 0.f;
    }
}

extern "C" void kernel_launch(void* const* d_in, const int* in_sizes, int n_in,
                              void* d_out, int out_size, void* d_ws, size_t ws_size,
                              hipStream_t stream)
{
    const float* lg     = (const float*)d_in[0];
    const float* rg     = (const float*)d_in[1];
    const float* kpl    = (const float*)d_in[2];
    const float* kpr    = (const float*)d_in[3];
    const float* scores = (const float*)d_in[4];
    const float* Q      = (const float*)d_in[5];
    float* out = (float*)d_out;

    char* ws = (char*)d_ws;
    float4* pts       = (float4*)ws;                  // 512000 B
    float*  partials  = (float*)(ws + 512000);        // 1000*8*4 = 32000 B
    float*  batch_acc = (float*)(ws + 544000);        // 16*4*4 = 256 B

    point_kernel<<<PT_BLOCKS, 256, 0, stream>>>(lg, rg, kpl, kpr, scores, Q,
                                                pts, partials, batch_acc);
    knn_kernel<<<dim3(KNN_BX, BB), 256, 0, stream>>>(pts, batch_acc);
    final_kernel<<<1, 256, 0, stream>>>(partials, batch_acc, out);
}

// Round 3
// 225.682 us; speedup vs baseline: 1.2595x; 1.2595x over previous
//
#include <hip/hip_runtime.h>

#define BB 16
#define NN 2000
#define HH 720
#define WW 1280
#define NPT (BB*NN)           // 32000 keypoints
#define PT_BLOCKS (NPT/32)    // 1000 blocks, 4 waves x 8 points each
#define PPT 4                 // points per thread (knn)
#define NCHUNK 16             // chunk-lanes per point-quad
#define CK (NN/NCHUNK)        // 125 m's per chunk-lane
#define KNN_BLOCKS ((NN + 63) / 64)   // 32 blocks of 64 points per batch

static __device__ __forceinline__ unsigned u_min(unsigned a, unsigned b){ return a < b ? a : b; }
static __device__ __forceinline__ unsigned u_max(unsigned a, unsigned b){ return a > b ? a : b; }

// sorted top-5 insert (ascending uint keys), min/max network, 9 ops
__device__ __forceinline__ void ins5(unsigned K[5], unsigned u) {
    K[4] = u_min(K[4], u_max(K[3], u));
    K[3] = u_min(K[3], u_max(K[2], u));
    K[2] = u_min(K[2], u_max(K[1], u));
    K[1] = u_min(K[1], u_max(K[0], u));
    K[0] = u_min(K[0], u);
}

// ---------------- bilinear sample, exact reference semantics (fallback) -----
__device__ __forceinline__ float bilin(const float* __restrict__ im, float px, float py) {
    px = fminf(fmaxf(px, 0.f), (float)(WW - 1));
    py = fminf(fmaxf(py, 0.f), (float)(HH - 1));
    float x0f = floorf(px), y0f = floorf(py);
    float fx = px - x0f, fy = py - y0f;
    int x0 = min(max((int)x0f, 0), WW - 1);
    int x1 = min(x0 + 1, WW - 1);
    int y0 = min(max((int)y0f, 0), HH - 1);
    int y1 = min(y0 + 1, HH - 1);
    const float* r0 = im + (size_t)y0 * WW;
    const float* r1 = im + (size_t)y1 * WW;
    float v00 = r0[x0], v01 = r0[x1], v10 = r1[x0], v11 = r1[x1];
    return (v00 * (1.f - fx) + v01 * fx) * (1.f - fy)
         + (v10 * (1.f - fx) + v11 * fx) * fy;
}

// ---------------- Kernel A: patch loss + projection (unchanged from R2) -----
__global__ __launch_bounds__(256) void point_kernel(
    const float* __restrict__ lg, const float* __restrict__ rg,
    const float* __restrict__ kpl, const float* __restrict__ kpr,
    const float* __restrict__ scores, const float* __restrict__ Q,
    float4* __restrict__ pts, float* __restrict__ partials,
    float* __restrict__ batch_acc)
{
    if (blockIdx.x == 0 && threadIdx.x < BB * 4) batch_acc[threadIdx.x] = 0.f;

    int wave = threadIdx.x >> 6, lane = threadIdx.x & 63;
    int rr = lane / 7, ci = lane - rr * 7;      // sample (row,col) for lane<49
    int s00 = lane + rr;                        // = rr*8+ci in 8x8 region
    if (s00 > 54) s00 = 54;                     // keep shfl idx valid for lanes>=49
    int reg_r = lane >> 3, reg_c = lane & 7;    // region-load position

    float a0=0.f,a1=0.f,a2=0.f,a3=0.f,a4=0.f,a5=0.f,a6=0.f;

    for (int it = 0; it < 8; ++it) {
        int pt = blockIdx.x * 32 + wave * 8 + it;
        int b = pt / NN;
        const float* iml = lg + (size_t)b * (HH * WW);
        const float* imr = rg + (size_t)b * (HH * WW);
        float kxl = kpl[2*pt], kyl = kpl[2*pt+1];
        float kxr = kpr[2*pt], kyr = kpr[2*pt+1];
        float sc  = scores[pt];

        // ---- left patch ----
        float flx = floorf(kxl), fly = floorf(kyl);
        int xbl = (int)flx - 3, ybl = (int)fly - 3;
        float fxl = kxl - flx, fyl = kyl - fly;
        float vl = 0.f;
        if (xbl >= 0 && xbl <= WW-8 && ybl >= 0 && ybl <= HH-8) {  // wave-uniform
            float reg = iml[(size_t)(ybl + reg_r) * WW + xbl + reg_c];
            float v00 = __shfl(reg, s00,     64);
            float v01 = __shfl(reg, s00 + 1, 64);
            float v10 = __shfl(reg, s00 + 8, 64);
            float v11 = __shfl(reg, s00 + 9, 64);
            vl = (v00*(1.f-fxl) + v01*fxl)*(1.f-fyl) + (v10*(1.f-fxl) + v11*fxl)*fyl;
        } else if (lane < 49) {
            vl = bilin(iml, kxl + (float)(ci-3), kyl + (float)(rr-3));
        }
        // ---- right patch ----
        float frx = floorf(kxr), fry = floorf(kyr);
        int xbr = (int)frx - 3, ybr = (int)fry - 3;
        float fxr = kxr - frx, fyr = kyr - fry;
        float vr = 0.f;
        if (xbr >= 0 && xbr <= WW-8 && ybr >= 0 && ybr <= HH-8) {  // wave-uniform
            float reg = imr[(size_t)(ybr + reg_r) * WW + xbr + reg_c];
            float v00 = __shfl(reg, s00,     64);
            float v01 = __shfl(reg, s00 + 1, 64);
            float v10 = __shfl(reg, s00 + 8, 64);
            float v11 = __shfl(reg, s00 + 9, 64);
            vr = (v00*(1.f-fxr) + v01*fxr)*(1.f-fyr) + (v10*(1.f-fxr) + v11*fxr)*fyr;
        } else if (lane < 49) {
            vr = bilin(imr, kxr + (float)(ci-3), kyr + (float)(rr-3));
        }

        float adiff = (lane < 49) ? fabsf(vl - vr) : 0.f;
        float cl = __shfl(vl, 24, 64);   // center sample (3,3)
        float cr = __shfl(vr, 24, 64);
        #pragma unroll
        for (int off = 32; off > 0; off >>= 1) adiff += __shfl_down(adiff, off, 64);

        if (lane == 0) {
            float diff = adiff / 49.f;
            float isb  = (cl > 0.02f) ? 1.f : 0.f;   // BRIGHT
            float w    = sc * isb;
            float ydiff = fabsf(kyl - kyr);
            float dc = fabsf(cl - cr);
            float sl1 = (dc < 1.f) ? 0.5f * dc * dc : dc - 0.5f;

            const float* q = Q + b * 16;
            float dsp = kxl - kxr;
            float p0 = q[0]*kxl + q[1]*kyl + q[2]*dsp  + q[3];
            float p1 = q[4]*kxl + q[5]*kyl + q[6]*dsp  + q[7];
            float p2 = q[8]*kxl + q[9]*kyl + q[10]*dsp + q[11];
            float p3 = q[12]*kxl + q[13]*kyl + q[14]*dsp + q[15];
            float Wc = fmaxf(p3, 1e-6f);
            float X = p0 / Wc, Y = p1 / Wc, Z = p2 / Wc;
            bool valid = (Z > 100.f) && (Z < 30000.f) && (sc > 0.1f);
            float x  = X / 1000.f;
            float hh = Y / 1000.f;
            float y  = Z / 1000.f;
            float sq = x * x + y * y;
            if (!valid) { x = 0.f; y = 0.f; sq = 1e18f; }   // sentinel
            pts[pt] = make_float4(x, y, sq, hh);

            a0 += sc;  a1 += ydiff * sc;  a2 += ydiff;
            a3 += w;   a4 += diff * w;    a5 += sl1 * w;
            a6 += (sc > 0.1f) ? 1.f : 0.f;
        }
    }

    __shared__ float red[4][7];
    if (lane == 0) {
        red[wave][0]=a0; red[wave][1]=a1; red[wave][2]=a2; red[wave][3]=a3;
        red[wave][4]=a4; red[wave][5]=a5; red[wave][6]=a6;
    }
    __syncthreads();
    if (threadIdx.x < 8) {
        int k = threadIdx.x;
        float v = 0.f;
        if (k < 7) v = red[0][k] + red[1][k] + red[2][k] + red[3][k];
        partials[blockIdx.x * 8 + k] = v;
    }
}

// ---------------- Kernel B: KNN, 4 points/thread, conflict-free stagger -----
// block = 256 threads = 4 waves; wave = 4 quads (qi=lane>>4) x 16 chunks (c=lane&15)
// quad owns 4 consecutive points; chunk c scans m in [c*125, (c+1)*125)
__global__ __launch_bounds__(256) void knn_kernel(
    const float4* __restrict__ pts, float* __restrict__ batch_acc)
{
    __shared__ float4 tile[NN];   // 32 KB
    int b = blockIdx.y;
    for (int i = threadIdx.x; i < NN; i += 256) tile[i] = pts[b * NN + i];
    __syncthreads();

    int lane = threadIdx.x & 63, wave = threadIdx.x >> 6;
    int qi = lane >> 4;           // quad in wave (0..3)
    int c  = lane & 15;           // chunk id (0..15)
    int n0 = blockIdx.x * 64 + (wave * 4 + qi) * PPT;

    unsigned K[PPT][5];
    float nx2[PPT], ny2[PPT], sqn[PPT];
    bool act[PPT];
    #pragma unroll
    for (int j = 0; j < PPT; ++j) {
        int n = n0 + j;
        float4 me = (n < NN) ? tile[n] : make_float4(0.f, 0.f, 1e18f, 0.f);
        act[j] = (me.z < 1e17f);
        nx2[j] = -2.f * me.x; ny2[j] = -2.f * me.y; sqn[j] = me.z;
        #pragma unroll
        for (int t = 0; t < 5; ++t) K[j][t] = 0xFFFFFFFFu;
    }

    int mbase = c * CK;
    int mm2 = (c & 1) * 4;        // bank stagger: 16 addrs land on distinct 4-bank groups (2-way, free)
    #pragma unroll 5
    for (int mm = 0; mm < CK; ++mm) {
        int m = mbase + mm2;
        mm2 = (mm2 + 1 == CK) ? 0 : mm2 + 1;
        float4 o = tile[m];
        #pragma unroll
        for (int j = 0; j < PPT; ++j) {
            float t = fmaf(ny2[j], o.y, o.z);
            t = fmaf(nx2[j], o.x, t);
            float d2 = fmaxf(t + sqn[j], 1e-12f);
            unsigned u = (__float_as_uint(d2) & 0xFFFFF800u) | (unsigned)m;
            u = (m == n0 + j) ? 0xFFFFFFFFu : u;   // exclude self in-loop
            ins5(K[j], u);
        }
    }

    // merge the 16 chunk lists of each quad (xor offsets stay in the 16-lane group)
    #pragma unroll
    for (int off = 1; off < 16; off <<= 1) {
        #pragma unroll
        for (int j = 0; j < PPT; ++j) {
            unsigned B0 = (unsigned)__shfl_xor((int)K[j][0], off, 64);
            unsigned B1 = (unsigned)__shfl_xor((int)K[j][1], off, 64);
            unsigned B2 = (unsigned)__shfl_xor((int)K[j][2], off, 64);
            unsigned B3 = (unsigned)__shfl_xor((int)K[j][3], off, 64);
            unsigned B4 = (unsigned)__shfl_xor((int)K[j][4], off, 64);
            ins5(K[j], B0); ins5(K[j], B1); ins5(K[j], B2); ins5(K[j], B3); ins5(K[j], B4);
        }
    }

    float ls = 0.f, pen = 0.f, hacc = 0.f, cnt = 0.f;
    if (c == 0) {
        #pragma unroll
        for (int j = 0; j < PPT; ++j) {
            int n = n0 + j;
            if (n < NN && act[j]) {
                float4 me = tile[n];
                float hsum = 0.f;
                #pragma unroll
                for (int t = 0; t < 5; ++t) {
                    int idx = (int)(K[j][t] & 2047u);
                    float4 o = tile[idx];
                    float dot = me.x * o.x + me.y * o.y;
                    float d2 = (me.z + o.z) - 2.f * dot;        // exact recompute
                    float nd = fmaxf(sqrtf(fmaxf(d2, 1e-12f)), 0.001f);
                    hsum += o.w;
                    pen  += fmaxf(fabsf(o.w - me.w) / nd - 0.4f, 0.f);
                }
                float lm = hsum / 5.f;
                float dd = fabsf(me.w - lm);
                ls += (dd < 0.01f) ? 0.5f * dd * dd / 0.01f : dd - 0.005f;
                hacc += me.w;
                cnt  += 1.f;
            }
        }
    }
    // reduce active lanes {0,16,32,48} -> lane 0
    ls   += __shfl_down(ls,   32, 64);  pen  += __shfl_down(pen,  32, 64);
    hacc += __shfl_down(hacc, 32, 64);  cnt  += __shfl_down(cnt,  32, 64);
    ls   += __shfl_down(ls,   16, 64);  pen  += __shfl_down(pen,  16, 64);
    hacc += __shfl_down(hacc, 16, 64);  cnt  += __shfl_down(cnt,  16, 64);
    if (lane == 0) {
        atomicAdd(&batch_acc[b * 4 + 0], cnt);
        atomicAdd(&batch_acc[b * 4 + 1], ls);
        atomicAdd(&batch_acc[b * 4 + 2], pen);
        atomicAdd(&batch_acc[b * 4 + 3], hacc);
    }
}

// ---------------- Kernel C: final scalar epilogue ---------------------------
__global__ __launch_bounds__(256) void final_kernel(
    const float* __restrict__ partials, const float* __restrict__ batch_acc,
    float* __restrict__ out)
{
    float s[8] = {0,0,0,0,0,0,0,0};
    for (int r = threadIdx.x; r < PT_BLOCKS; r += 256) {
        #pragma unroll
        for (int k = 0; k < 8; ++k) s[k] += partials[r * 8 + k];
    }
    #pragma unroll
    for (int off = 32; off > 0; off >>= 1) {
        #pragma unroll
        for (int k = 0; k < 8; ++k) s[k] += __shfl_down(s[k], off, 64);
    }
    __shared__ float wsum_s[4][8];
    int wv = threadIdx.x >> 6, lane = threadIdx.x & 63;
    if (lane == 0) {
        #pragma unroll
        for (int k = 0; k < 8; ++k) wsum_s[wv][k] = s[k];
    }
    __syncthreads();
    if (threadIdx.x == 0) {
        float t[8];
        #pragma unroll
        for (int k = 0; k < 8; ++k)
            t[k] = wsum_s[0][k] + wsum_s[1][k] + wsum_s[2][k] + wsum_s[3][k];
        float ssc = t[0], yds = t[1], yd = t[2], wsum = t[3], dw = t[4], iw = t[5], cnts = t[6];

        float l_epi = (ssc > 1e-4f) ? yds / fmaxf(ssc, 1e-12f) : yd / (float)NPT;
        float safe = fmaxf(wsum, 1e-12f);
        float l_photo = (wsum > 1e-4f) ? (dw / safe + iw / safe) : 0.f;

        float als = 0.f, alsl = 0.f, alz = 0.f, okc = 0.f;
        for (int b = 0; b < BB; ++b) {
            float nvf  = batch_acc[b * 4 + 0];
            float lsb  = batch_acc[b * 4 + 1];
            float penb = batch_acc[b * 4 + 2];
            float hb   = batch_acc[b * 4 + 3];
            float nv = fmaxf(nvf, 1.f);
            float ok = (nvf >= 10.f) ? 1.f : 0.f;
            als  += ok * (lsb / nv);
            alsl += ok * (penb / (nv * 5.f));   // K = 5
            alz  += ok * fabsf(hb / nv);
            okc  += ok;
        }
        float nb = fmaxf(okc, 1.f);
        bool gate = (cnts >= 10.f) && (okc > 0.f);
        out[0] = l_photo;
        out[1] = l_epi;
        out[2] = gate ? als / nb : 0.f;
        out[3] = gate ? alsl / nb : 0.f;
        out[4] = gate ? alz / nb : 0.f;
    }
}

extern "C" void kernel_launch(void* const* d_in, const int* in_sizes, int n_in,
                              void* d_out, int out_size, void* d_ws, size_t ws_size,
                              hipStream_t stream)
{
    const float* lg     = (const float*)d_in[0];
    const float* rg     = (const float*)d_in[1];
    const float* kpl    = (const float*)d_in[2];
    const float* kpr    = (const float*)d_in[3];
    const float* scores = (const float*)d_in[4];
    const float* Q      = (const float*)d_in[5];
    float* out = (float*)d_out;

    char* ws = (char*)d_ws;
    float4* pts       = (float4*)ws;                  // 512000 B
    float*  partials  = (float*)(ws + 512000);        // 1000*8*4 = 32000 B
    float*  batch_acc = (float*)(ws + 544000);        // 16*4*4 = 256 B

    point_kernel<<<PT_BLOCKS, 256, 0, stream>>>(lg, rg, kpl, kpr, scores, Q,
                                                pts, partials, batch_acc);
    knn_kernel<<<dim3(KNN_BLOCKS, BB), 256, 0, stream>>>(pts, batch_acc);
    final_kernel<<<1, 256, 0, stream>>>(partials, batch_acc, out);
}